// Round 2
// baseline (430.055 us; speedup 1.0000x reference)
//
#include <hip/hip_runtime.h>

#define NV 16384
#define RPW 4        // rows of L per wave
#define WAVES 4      // waves per block
#define THREADS (WAVES * 64)
#define JSTEP 256    // 64 lanes * 4 floats per iteration

__global__ __launch_bounds__(THREADS, 3) void lap_loss_kernel(
    const float* __restrict__ x, const float* __restrict__ L,
    float* __restrict__ out) {
  const int lane = threadIdx.x & 63;
  const int wid  = blockIdx.x * WAVES + (threadIdx.x >> 6);
  const size_t i0 = (size_t)wid * RPW;

  float acc[RPW][12];
#pragma unroll
  for (int r = 0; r < RPW; ++r)
#pragma unroll
    for (int k = 0; k < 12; ++k) acc[r][k] = 0.f;

  const float* Lbase = L + i0 * NV;
  const int j0 = lane * 4;  // this lane's 4 contiguous j's within the tile

  // ---- L double-buffer: prologue load of tile 0 ----
  float4 lv[RPW], ln[RPW];
#pragma unroll
  for (int r = 0; r < RPW; ++r)
    lv[r] = *(const float4*)(Lbase + (size_t)r * NV + j0);

  // FMA body for one tile: uses lv[] and x at tile base jb.
  auto body = [&](int jb) {
    // x[b][jb+j0 .. jb+j0+3][0..2] = 12 contiguous floats, 16B-aligned
    float xf[4][12];
#pragma unroll
    for (int b = 0; b < 4; ++b) {
      const float4* xp =
          (const float4*)(x + ((size_t)b * NV + jb + j0) * 3);
      float4 q0 = xp[0], q1 = xp[1], q2 = xp[2];
      xf[b][0] = q0.x; xf[b][1] = q0.y; xf[b][2]  = q0.z; xf[b][3]  = q0.w;
      xf[b][4] = q1.x; xf[b][5] = q1.y; xf[b][6]  = q1.z; xf[b][7]  = q1.w;
      xf[b][8] = q2.x; xf[b][9] = q2.y; xf[b][10] = q2.z; xf[b][11] = q2.w;
    }
#pragma unroll
    for (int r = 0; r < RPW; ++r) {
      float lf[4] = {lv[r].x, lv[r].y, lv[r].z, lv[r].w};
#pragma unroll
      for (int jj = 0; jj < 4; ++jj)
#pragma unroll
        for (int b = 0; b < 4; ++b)
#pragma unroll
          for (int d = 0; d < 3; ++d)
            acc[r][b * 3 + d] =
                fmaf(lf[jj], xf[b][jj * 3 + d], acc[r][b * 3 + d]);
    }
  };

#pragma unroll 1
  for (int jb = 0; jb < NV - JSTEP; jb += JSTEP) {
    // prefetch next L tile while current tile computes
#pragma unroll
    for (int r = 0; r < RPW; ++r)
      ln[r] = *(const float4*)(Lbase + (size_t)r * NV + jb + JSTEP + j0);
    body(jb);
#pragma unroll
    for (int r = 0; r < RPW; ++r) lv[r] = ln[r];
  }
  body(NV - JSTEP);  // last tile, no prefetch

  // ---- butterfly-reduce each of the RPW*12 partial sums, square, commit ----
  float s[4] = {0.f, 0.f, 0.f, 0.f};
#pragma unroll
  for (int r = 0; r < RPW; ++r)
#pragma unroll
    for (int k = 0; k < 12; ++k) {
      float v = acc[r][k];
#pragma unroll
      for (int off = 32; off > 0; off >>= 1)
        v += __shfl_xor(v, off, 64);
      s[k / 3] += v * v;
    }

  if (lane == 0) {
#pragma unroll
    for (int b = 0; b < 4; ++b) atomicAdd(&out[b], s[b]);
  }
}

extern "C" void kernel_launch(void* const* d_in, const int* in_sizes, int n_in,
                              void* d_out, int out_size, void* d_ws, size_t ws_size,
                              hipStream_t stream) {
  const float* x = (const float*)d_in[0];
  const float* L = (const float*)d_in[1];
  float* out = (float*)d_out;

  // Harness poisons d_out with 0xAA and never re-poisons between replays.
  hipMemsetAsync(out, 0, out_size * sizeof(float), stream);

  const int nwaves  = NV / RPW;          // 4096
  const int nblocks = nwaves / WAVES;    // 1024
  lap_loss_kernel<<<nblocks, THREADS, 0, stream>>>(x, L, out);
}

// Round 3
// 240.654 us; speedup vs baseline: 1.7870x; 1.7870x over previous
//
#include <hip/hip_runtime.h>

#define NV 16384
#define BROWS 16          // L rows per block
#define JT 256            // j-tile width (floats)
#define NT (NV / JT)      // 64 tiles
#define THREADS 256

typedef const __attribute__((address_space(1))) void* as1_ptr;
typedef __attribute__((address_space(3))) void* as3_ptr;

// Direct HBM -> LDS, 16B per lane. LDS dest is the WAVE-UNIFORM base;
// hardware adds lane*16 implicitly. Global src is per-lane.
__device__ __forceinline__ void gload_lds16(const float* g, float* l) {
  __builtin_amdgcn_global_load_lds((as1_ptr)g, (as3_ptr)l, 16, 0, 0);
}

__global__ __launch_bounds__(THREADS, 4) void lap_loss_kernel(
    const float* __restrict__ x, const float* __restrict__ L,
    float* __restrict__ out) {
  __shared__ float lbuf[2][BROWS * JT];  // 2 x 16KB double buffer

  const int lane = threadIdx.x & 63;
  const int w    = threadIdx.x >> 6;     // wave id == batch index b
  const size_t i0 = (size_t)blockIdx.x * BROWS;

  // wave w stages rows i0+4w .. i0+4w+3; lane covers 4 floats of each row
  const float* gL[4];
#pragma unroll
  for (int r = 0; r < 4; ++r)
    gL[r] = L + (i0 + 4 * w + r) * NV + lane * 4;

  // wave w's x stream: x[w][j][d], lane covers j-quad 4*lane (12 floats, 48B)
  const float* gx = x + (size_t)w * NV * 3 + lane * 12;

  float acc[BROWS][3];
#pragma unroll
  for (int r = 0; r < BROWS; ++r)
#pragma unroll
    for (int d = 0; d < 3; ++d) acc[r][d] = 0.f;

  // ---- prologue: x(0) loads, then the 4 gl_lds for tile 0 ----
  float4 xc0 = *(const float4*)(gx + 0);
  float4 xc1 = *(const float4*)(gx + 4);
  float4 xc2 = *(const float4*)(gx + 8);
  asm volatile("" ::: "memory");
#pragma unroll
  for (int r = 0; r < 4; ++r)
    gload_lds16(gL[r], &lbuf[0][(4 * w + r) * JT]);

#pragma unroll 1
  for (int t = 0; t < NT - 1; ++t) {
    const int cur = t & 1;

    // prefetch x(t+1) into regs
    const float* gxn = gx + (size_t)(t + 1) * JT * 3;
    float4 xn0 = *(const float4*)(gxn + 0);
    float4 xn1 = *(const float4*)(gxn + 4);
    float4 xn2 = *(const float4*)(gxn + 8);
    asm volatile("" ::: "memory");

    // prefetch L(t+1) -> other LDS buffer (4 gl_lds, last 4 vmem ops)
#pragma unroll
    for (int r = 0; r < 4; ++r)
      gload_lds16(gL[r] + (size_t)(t + 1) * JT, &lbuf[cur ^ 1][(4 * w + r) * JT]);

    // drain everything EXCEPT the 4 gl_lds just issued (counted vmcnt:
    // previous tile's gl_lds + all x loads complete; prefetch stays in flight)
    asm volatile("s_waitcnt vmcnt(4)" ::: "memory");
    __builtin_amdgcn_s_barrier();
    asm volatile("" ::: "memory");

    // ---- compute tile t from lbuf[cur] ----
    {
      const float xf[12] = {xc0.x, xc0.y, xc0.z, xc0.w,
                            xc1.x, xc1.y, xc1.z, xc1.w,
                            xc2.x, xc2.y, xc2.z, xc2.w};
#pragma unroll
      for (int r = 0; r < BROWS; ++r) {
        float4 lv = *(const float4*)&lbuf[cur][r * JT + lane * 4];
        const float lf[4] = {lv.x, lv.y, lv.z, lv.w};
#pragma unroll
        for (int jj = 0; jj < 4; ++jj)
#pragma unroll
          for (int d = 0; d < 3; ++d)
            acc[r][d] = fmaf(lf[jj], xf[jj * 3 + d], acc[r][d]);
      }
    }

    asm volatile("" ::: "memory");
    __builtin_amdgcn_s_barrier();  // all waves done reading lbuf[cur];
    asm volatile("" ::: "memory"); // next iter may overwrite it

    xc0 = xn0; xc1 = xn1; xc2 = xn2;
  }

  // ---- last tile: full drain, then compute ----
  asm volatile("s_waitcnt vmcnt(0)" ::: "memory");
  __builtin_amdgcn_s_barrier();
  asm volatile("" ::: "memory");
  {
    const int cur = (NT - 1) & 1;
    const float xf[12] = {xc0.x, xc0.y, xc0.z, xc0.w,
                          xc1.x, xc1.y, xc1.z, xc1.w,
                          xc2.x, xc2.y, xc2.z, xc2.w};
#pragma unroll
    for (int r = 0; r < BROWS; ++r) {
      float4 lv = *(const float4*)&lbuf[cur][r * JT + lane * 4];
      const float lf[4] = {lv.x, lv.y, lv.z, lv.w};
#pragma unroll
      for (int jj = 0; jj < 4; ++jj)
#pragma unroll
        for (int d = 0; d < 3; ++d)
          acc[r][d] = fmaf(lf[jj], xf[jj * 3 + d], acc[r][d]);
    }
  }

  // ---- butterfly-reduce each (row,d) partial over 64 lanes, square, commit ----
  float s = 0.f;
#pragma unroll
  for (int r = 0; r < BROWS; ++r)
#pragma unroll
    for (int d = 0; d < 3; ++d) {
      float v = acc[r][d];
#pragma unroll
      for (int off = 32; off > 0; off >>= 1)
        v += __shfl_xor(v, off, 64);
      s += v * v;
    }

  if (lane == 0) atomicAdd(&out[w], s);  // wave w owns batch w
}

extern "C" void kernel_launch(void* const* d_in, const int* in_sizes, int n_in,
                              void* d_out, int out_size, void* d_ws, size_t ws_size,
                              hipStream_t stream) {
  const float* x = (const float*)d_in[0];
  const float* L = (const float*)d_in[1];
  float* out = (float*)d_out;

  // Harness poisons d_out with 0xAA and never re-poisons between replays.
  hipMemsetAsync(out, 0, out_size * sizeof(float), stream);

  const int nblocks = NV / BROWS;  // 1024 blocks, 4 per CU resident
  lap_loss_kernel<<<nblocks, THREADS, 0, stream>>>(x, L, out);
}